// Round 6
// baseline (96.936 us; speedup 1.0000x reference)
//
#include <hip/hip_runtime.h>

#define NB 32
#define NS 2048
// (1/sqrt(d_k)) * log2(e) folded into q so scores feed v_exp_f32 (2^x) directly
#define QS 0.72134752044448170367f

typedef _Float16 f16;
typedef _Float16 h2 __attribute__((ext_vector_type(2)));
typedef _Float16 h4 __attribute__((ext_vector_type(4)));
typedef _Float16 h8 __attribute__((ext_vector_type(8)));
typedef float f32x4 __attribute__((ext_vector_type(4)));

__device__ __forceinline__ h2 cvt_pk_f16(float a, float b) {
  return __builtin_bit_cast(h2, __builtin_amdgcn_cvt_pkrtz(a, b));
}

// LDS geometry (units: halves/f16):
//   main      : [1024][8]  f16 k-rows (16 B/row)            -> 8192 halves
//   transposed: [10][1032] f16, row d = dim (0-7), 8 = ones, 9 = zeros
//               stride 1032 halves (2064 B) to spread banks  -> 10320 halves
#define TR_STRIDE 1032
#define TR_BASE 8192
#define LDS_HALVES (8192 + 10 * 1032)
#define ZIDX (TR_BASE + 9 * TR_STRIDE)  // zeros row (also zero A-frag source)

// ---------------------------------------------------------------------------
// All-MFMA fused attention + 2-way SPLIT-K (R6).
//   R5 post-mortem: issue port only 61% busy at 4 waves/SIMD -- dependency
//   bubbles in the ds_read -> scoreMFMA -> exp -> PV-MFMA chain. Total wave
//   count was pinned at 4096 (= 65536 q / 16 q per wave). This round doubles
//   resident waves WITHOUT half-empty MFMA tiles via split-K:
//   - block = 512 thr = 8 waves; block owns 64 q (4 tiles of 16).
//     wave w: q-tile qt = w&3, k-half h = w>>2. Per 1024-row LDS chunk,
//     half-h waves process rows [h*512, h*512+512) -- both halves active
//     every chunk; per-wave work halves (32 steps of 32 k-rows).
//   - grid = 32 x 32 = 1024 blocks -> 4 blocks/CU (LDS 149.5/160 KB),
//     32 waves/CU = 8 waves/SIMD. Same total VALU/exp work, 2x overlap.
//   - SCORES via MFMA (R5): A slots (g=0,j<4) = K[.][d], B slots (g=0,j<4)
//     = Q[n][d]*QS (loop-invariant regs), zeros elsewhere (zeros-row reads).
//     Correct for ANY HW slot map since kappa_A == kappa_B (R4/R5-proven).
//   - D layout (m89): col = lane&15 = q, row = 4g+reg -> lane holds
//     P[k=kb+16h'+4g+r][q=n]; used directly as PV B-frag by building the PV
//     A-frag (h^T rows from transposed LDS) with the SAME (g,j)->k formula.
//   - PV A rows: m<4 -> dim(head*4+m); m==4 -> ones (denominator); else 0.
//   - epilogue: wave pairs (w, w+4) merge C via LDS (stride 9 floats ->
//     2-way bank aliasing = free), then per-wave normalize/project/store.
// ---------------------------------------------------------------------------
__global__ __launch_bounds__(512, 8) void attn_fused_kernel(
    const float* __restrict__ x, const float* __restrict__ theta,
    const float* __restrict__ Wout, float* __restrict__ outp) {
  __shared__ __align__(16) f16 lds[LDS_HALVES];

  const int b = blockIdx.y;
  const int t = threadIdx.x;
  const int w = t >> 6;
  const int lane = t & 63;
  const int g = lane >> 4;   // 16-lane group
  const int n = lane & 15;   // q-column within the wave's q-tile
  const int qt = w & 3;      // q-tile within block
  const int h = w >> 2;      // k-half (0: rows 0-511 of chunk, 1: 512-1023)

  float th[8];
#pragma unroll
  for (int e = 0; e < 8; ++e) th[e] = theta[e];

  // ---- stage chunk 0 (k rows 0..1023): main f16 rows + transposed copy ----
#pragma unroll
  for (int i = 0; i < 2; ++i) {
    const int l = t + 512 * i;
    const float4* xr = (const float4*)(x + ((size_t)b * NS + l) * 8);
    float4 lo = xr[0], hi = xr[1];
    h8 hv;
    hv[0] = (f16)__cosf(lo.x + th[0]);
    hv[1] = (f16)__cosf(lo.y + th[1]);
    hv[2] = (f16)__cosf(lo.z + th[2]);
    hv[3] = (f16)__cosf(lo.w + th[3]);
    hv[4] = (f16)__cosf(hi.x + th[4]);
    hv[5] = (f16)__cosf(hi.y + th[5]);
    hv[6] = (f16)__cosf(hi.z + th[6]);
    hv[7] = (f16)__cosf(hi.w + th[7]);
    ((h8*)lds)[l] = hv;
#pragma unroll
    for (int e = 0; e < 8; ++e) lds[TR_BASE + e * TR_STRIDE + l] = hv[e];
    lds[TR_BASE + 8 * TR_STRIDE + l] = (f16)1.0f;  // ones row (denominator)
    lds[ZIDX + l] = (f16)0.0f;                     // zeros row
  }

  // ---- prefetch chunk 1 raw x into registers ----
  float4 pf[2][2];
#pragma unroll
  for (int i = 0; i < 2; ++i) {
    const int l = t + 512 * i;
    const float4* xr = (const float4*)(x + ((size_t)b * NS + 1024 + l) * 8);
    pf[i][0] = xr[0];
    pf[i][1] = xr[1];
  }

  // ---- loop-invariant score B-fragments: Q[n][d]*QS at (g=0, j<4) ----
  h8 Bq0, Bq1;
#pragma unroll
  for (int j = 0; j < 8; ++j) {
    Bq0[j] = (f16)0.f;
    Bq1[j] = (f16)0.f;
  }
  if (g == 0) {
    const float4* xq = (const float4*)(
        x + ((size_t)b * NS + blockIdx.x * 64 + qt * 16 + n) * 8);
    float4 lo = xq[0], hi = xq[1];
    Bq0[0] = (f16)(__cosf(lo.x + th[0]) * QS);
    Bq0[1] = (f16)(__cosf(lo.y + th[1]) * QS);
    Bq0[2] = (f16)(__cosf(lo.z + th[2]) * QS);
    Bq0[3] = (f16)(__cosf(lo.w + th[3]) * QS);
    Bq1[0] = (f16)(__cosf(hi.x + th[4]) * QS);
    Bq1[1] = (f16)(__cosf(hi.y + th[5]) * QS);
    Bq1[2] = (f16)(__cosf(hi.z + th[6]) * QS);
    Bq1[3] = (f16)(__cosf(hi.w + th[7]) * QS);
  }

  // score A-frag source: g==0 reads main k-rows of this wave's half
  // (advance 256 halves/step), g>0 reads the zeros row (constant addr).
  const int sini = (g == 0) ? (h * 512 + n) * 8 : ZIDX;
  const int sadv = (g == 0) ? 256 : 0;

  // PV A-frag source rows in the transposed copy, per head:
  const int d0 = (n < 4) ? n : ((n == 4) ? 8 : 9);
  const int d1 = (n < 4) ? (n + 4) : d0;
  const int t0ini = TR_BASE + d0 * TR_STRIDE + h * 512 + 4 * g;
  const int t1ini = TR_BASE + d1 * TR_STRIDE + h * 512 + 4 * g;

  const f32x4 Z = {0.f, 0.f, 0.f, 0.f};
  f32x4 C0 = Z;  // head0: rows 0-3 = dims, row 4 = den (col = q)
  f32x4 C1 = Z;  // head1

  __syncthreads();  // (1) chunk 0 staged

  for (int chunk = 0; chunk < 2; ++chunk) {
    if (chunk == 1) {
      __syncthreads();  // (2) chunk 0 fully consumed
#pragma unroll
      for (int i = 0; i < 2; ++i) {
        const int l = t + 512 * i;
        float4 lo = pf[i][0], hi = pf[i][1];
        h8 hv;
        hv[0] = (f16)__cosf(lo.x + th[0]);
        hv[1] = (f16)__cosf(lo.y + th[1]);
        hv[2] = (f16)__cosf(lo.z + th[2]);
        hv[3] = (f16)__cosf(lo.w + th[3]);
        hv[4] = (f16)__cosf(hi.x + th[4]);
        hv[5] = (f16)__cosf(hi.y + th[5]);
        hv[6] = (f16)__cosf(hi.z + th[6]);
        hv[7] = (f16)__cosf(hi.w + th[7]);
        ((h8*)lds)[l] = hv;
#pragma unroll
        for (int e = 0; e < 8; ++e) lds[TR_BASE + e * TR_STRIDE + l] = hv[e];
      }
      __syncthreads();  // (3) chunk 1 staged
    }

    int sc = sini;
    int tc0 = t0ini;
    int tc1 = t1ini;
#pragma unroll 2
    for (int step = 0; step < 16; ++step) {
      // ---- score A-fragments (K rows via group-0 lanes; zeros elsewhere)
      h4 k00 = *(const h4*)(lds + sc);        // row kb+n,     head0 dims
      h4 k10 = *(const h4*)(lds + sc + 4);    //               head1 dims
      h4 k01 = *(const h4*)(lds + sc + 128);  // row kb+16+n,  head0 dims
      h4 k11 = *(const h4*)(lds + sc + 132);  //               head1 dims
      // ---- PV A-fragments (h^T + ones/zeros rows), same (g,j)->k formula
      //      as the score-D-derived B-fragment: k = 16*(j>>2)+4g+(j&3)
      h4 a00 = *(const h4*)(lds + tc0);       // head0, cols kb+4g..+3
      h4 a01 = *(const h4*)(lds + tc0 + 16);  //        cols kb+16+4g..+3
      h4 a10 = *(const h4*)(lds + tc1);       // head1
      h4 a11 = *(const h4*)(lds + tc1 + 16);

      h8 A00, A01, A10, A11, V0, V1;
#pragma unroll
      for (int j = 0; j < 4; ++j) {
        A00[j] = k00[j];
        A01[j] = k01[j];
        A10[j] = k10[j];
        A11[j] = k11[j];
        A00[j + 4] = (f16)0.f;
        A01[j + 4] = (f16)0.f;
        A10[j + 4] = (f16)0.f;
        A11[j + 4] = (f16)0.f;
        V0[j] = a00[j];
        V0[j + 4] = a01[j];
        V1[j] = a10[j];
        V1[j + 4] = a11[j];
      }

      // ---- scores on the MFMA pipe: D rows = k (4g+reg), cols = q ----
      f32x4 S00 = __builtin_amdgcn_mfma_f32_16x16x32_f16(A00, Bq0, Z, 0, 0, 0);
      f32x4 S01 = __builtin_amdgcn_mfma_f32_16x16x32_f16(A01, Bq0, Z, 0, 0, 0);
      f32x4 S10 = __builtin_amdgcn_mfma_f32_16x16x32_f16(A10, Bq1, Z, 0, 0, 0);
      f32x4 S11 = __builtin_amdgcn_mfma_f32_16x16x32_f16(A11, Bq1, Z, 0, 0, 0);

      // ---- exp (trans pipe) + pack into the PV B-fragment ----
      h8 B0, B1;
      h2 p;
      p = cvt_pk_f16(__builtin_amdgcn_exp2f(S00[0]),
                     __builtin_amdgcn_exp2f(S00[1]));
      B0[0] = p[0];
      B0[1] = p[1];
      p = cvt_pk_f16(__builtin_amdgcn_exp2f(S00[2]),
                     __builtin_amdgcn_exp2f(S00[3]));
      B0[2] = p[0];
      B0[3] = p[1];
      p = cvt_pk_f16(__builtin_amdgcn_exp2f(S01[0]),
                     __builtin_amdgcn_exp2f(S01[1]));
      B0[4] = p[0];
      B0[5] = p[1];
      p = cvt_pk_f16(__builtin_amdgcn_exp2f(S01[2]),
                     __builtin_amdgcn_exp2f(S01[3]));
      B0[6] = p[0];
      B0[7] = p[1];
      p = cvt_pk_f16(__builtin_amdgcn_exp2f(S10[0]),
                     __builtin_amdgcn_exp2f(S10[1]));
      B1[0] = p[0];
      B1[1] = p[1];
      p = cvt_pk_f16(__builtin_amdgcn_exp2f(S10[2]),
                     __builtin_amdgcn_exp2f(S10[3]));
      B1[2] = p[0];
      B1[3] = p[1];
      p = cvt_pk_f16(__builtin_amdgcn_exp2f(S11[0]),
                     __builtin_amdgcn_exp2f(S11[1]));
      B1[4] = p[0];
      B1[5] = p[1];
      p = cvt_pk_f16(__builtin_amdgcn_exp2f(S11[2]),
                     __builtin_amdgcn_exp2f(S11[3]));
      B1[6] = p[0];
      B1[7] = p[1];

      // ---- PV (+denominator via ones-row) on the MFMA pipe ----
      C0 = __builtin_amdgcn_mfma_f32_16x16x32_f16(V0, B0, C0, 0, 0, 0);
      C1 = __builtin_amdgcn_mfma_f32_16x16x32_f16(V1, B1, C1, 0, 0, 0);

      sc += sadv;
      tc0 += 32;
      tc1 += 32;
    }
  }

  // ---- split-K pair merge (w <-> w+4) through LDS ----
  __syncthreads();  // (4) all waves done reading lds as k-tiles
  float* kvf = (float*)lds;
  if (h == 1) {
    // stride 9 floats: lanes i and i+32 alias (2-way = free), else distinct
    float* mb = kvf + ((size_t)(qt * 64 + lane)) * 9;
    mb[0] = C0[0];
    mb[1] = C0[1];
    mb[2] = C0[2];
    mb[3] = C0[3];
    mb[4] = C1[0];
    mb[5] = C1[1];
    mb[6] = C1[2];
    mb[7] = C1[3];
  }
  __syncthreads();  // (5)
  if (h == 0) {
    const float* mb = kvf + ((size_t)(qt * 64 + lane)) * 9;
    C0[0] += mb[0];
    C0[1] += mb[1];
    C0[2] += mb[2];
    C0[3] += mb[3];
    C1[0] += mb[4];
    C1[1] += mb[5];
    C1[2] += mb[6];
    C1[3] += mb[7];

    // ---- epilogue: C cols = q (lane&15), rows = 4*(lane>>4)+reg ----
    const float den0 = __shfl(C0[0], 16 + n, 64);  // row 4 = ones-row sum
    const float den1 = __shfl(C1[0], 16 + n, 64);
    if (lane < 16) {  // group 0 holds rows 0-3 = numerator dims
      const float i0 = 1.0f / den0, i1 = 1.0f / den1;
      float m8[8] = {C0[0] * i0, C0[1] * i0, C0[2] * i0, C0[3] * i0,
                     C1[0] * i1, C1[1] * i1, C1[2] * i1, C1[3] * i1};
      float o[8];
#pragma unroll
      for (int e = 0; e < 8; ++e) {
        float s = 0.f;
#pragma unroll
        for (int f = 0; f < 8; ++f) s += m8[f] * Wout[e * 8 + f];
        o[e] = s;
      }
      const int q = blockIdx.x * 64 + qt * 16 + n;
      float4* op = (float4*)(outp + ((size_t)b * NS + q) * 8);
      op[0] = make_float4(o[0], o[1], o[2], o[3]);
      op[1] = make_float4(o[4], o[5], o[6], o[7]);
    }
  }
}

extern "C" void kernel_launch(void* const* d_in, const int* in_sizes, int n_in,
                              void* d_out, int out_size, void* d_ws,
                              size_t ws_size, hipStream_t stream) {
  const float* x = (const float*)d_in[0];      // [32, 2048, 8]
  const float* theta = (const float*)d_in[1];  // [8]
  const float* W = (const float*)d_in[2];      // [8, 8]
  float* out = (float*)d_out;                  // [32, 2048, 8]
  (void)d_ws;
  (void)ws_size;

  // 1024 blocks (32 q-supertiles x 32 batches) of 8 waves; 37.4 KB LDS each
  // -> 4 blocks/CU (149.5/160 KB), 32 waves/CU = 8 waves/SIMD.
  attn_fused_kernel<<<dim3(NS / 64, NB), 512, 0, stream>>>(x, theta, W, out);
}

// Round 7
// 89.211 us; speedup vs baseline: 1.0866x; 1.0866x over previous
//
#include <hip/hip_runtime.h>

#define NB 32
#define NS 2048
// (1/sqrt(d_k)) * log2(e) folded into q so scores feed v_exp_f32 (2^x) directly
#define QS 0.72134752044448170367f

typedef _Float16 f16;
typedef _Float16 h2 __attribute__((ext_vector_type(2)));
typedef _Float16 h4 __attribute__((ext_vector_type(4)));
typedef _Float16 h8 __attribute__((ext_vector_type(8)));
typedef float f32x4 __attribute__((ext_vector_type(4)));

__device__ __forceinline__ h2 cvt_pk_f16(float a, float b) {
  return __builtin_bit_cast(h2, __builtin_amdgcn_cvt_pkrtz(a, b));
}
__device__ __forceinline__ f32x4 mfma16(h4 a, h4 b, f32x4 c) {
  return __builtin_amdgcn_mfma_f32_16x16x16f16(a, b, c, 0, 0, 0);
}

// LDS geometry (units: halves/f16):
//   main      : [1024][8]  f16 k-rows (16 B/row)            -> 8192 halves
//   transposed: [10][1032] f16, row d = dim (0-7), 8 = ones, 9 = zeros
//               stride 1032 halves (2064 B) to spread banks  -> 10320 halves
#define TR_STRIDE 1032
#define TR_BASE 8192
#define LDS_HALVES (8192 + 10 * 1032)
#define ZIDX (TR_BASE + 9 * TR_STRIDE)  // zeros row (zero-fragment source)

// ---------------------------------------------------------------------------
// All-MFMA fused attention, K=16 shape (R7).
//   R6 post-mortem: launch_bounds(512,8) -> 64-reg cap incl AGPRs -> spills
//   (WRITE_SIZE 2->36 MB). Reverted to the R5 shell (4 waves/SIMD, no
//   split-K). R5 post-mortem: ~90 of 254 busy cyc/step were h8 fragment
//   PACKING (zero-padding movs, h4->h8 interleaves). This round removes all
//   packing by switching to v_mfma_f32_16x16x16_f16 (A=B=4 halves=2 VGPRs):
//   - SCORES: per 16 k-rows per head, A = K-rows (lane m=lane&15 reads
//     main[(r0+m)*8 + head*4], one b128 covers BOTH heads; g>0 lanes read
//     the zeros row), B = Q[n][d]*QS (loop-invariant regs; g>0 lanes zero).
//     kappa_A == kappa_B for any HW slot map -> dot over d_k=4 exact
//     (R4/R5-proven cancellation argument).
//   - D layout (m89, shape-determined): col = lane&15 = q, row = 4g+reg.
//     So lane holds S[r0+4g+r][n] -- exp+cvt_pk gives an h4 that IS the PV
//     B-fragment (slot j of group g = k-slot 4g+j, matching documented
//     A/B layout symmetry).
//   - PV: A = h^T rows (m<4 -> dim head*4+m; m==4 -> ones = denominator;
//     else zeros), one ds_read_b64 per head from the transposed copy.
//   - per 16k both heads: 1 b128 + 2 b64 ds_reads, 4 MFMA, 8 exp, 4 cvt,
//     ZERO packing movs.
//   - epilogue per-wave: group 0 lanes hold dims (rows 0-3), row 4 = den.
// ---------------------------------------------------------------------------
__global__ __launch_bounds__(512, 4) void attn_fused_kernel(
    const float* __restrict__ x, const float* __restrict__ theta,
    const float* __restrict__ Wout, float* __restrict__ outp) {
  __shared__ __align__(16) f16 lds[LDS_HALVES];

  const int b = blockIdx.y;
  const int t = threadIdx.x;
  const int w = t >> 6;
  const int lane = t & 63;
  const int g = lane >> 4;  // 16-lane group
  const int n = lane & 15;  // q-col (B role) AND k/dim-row m (A role)

  float th[8];
#pragma unroll
  for (int e = 0; e < 8; ++e) th[e] = theta[e];

  // ---- stage chunk 0 (k rows 0..1023): main f16 rows + transposed copy ----
#pragma unroll
  for (int i = 0; i < 2; ++i) {
    const int l = t + 512 * i;
    const float4* xr = (const float4*)(x + ((size_t)b * NS + l) * 8);
    float4 lo = xr[0], hi = xr[1];
    h8 hv;
    hv[0] = (f16)__cosf(lo.x + th[0]);
    hv[1] = (f16)__cosf(lo.y + th[1]);
    hv[2] = (f16)__cosf(lo.z + th[2]);
    hv[3] = (f16)__cosf(lo.w + th[3]);
    hv[4] = (f16)__cosf(hi.x + th[4]);
    hv[5] = (f16)__cosf(hi.y + th[5]);
    hv[6] = (f16)__cosf(hi.z + th[6]);
    hv[7] = (f16)__cosf(hi.w + th[7]);
    ((h8*)lds)[l] = hv;
#pragma unroll
    for (int e = 0; e < 8; ++e) lds[TR_BASE + e * TR_STRIDE + l] = hv[e];
    lds[TR_BASE + 8 * TR_STRIDE + l] = (f16)1.0f;  // ones row (denominator)
    lds[ZIDX + l] = (f16)0.0f;                     // zeros row
  }

  // ---- prefetch chunk 1 raw x into registers ----
  float4 pf[2][2];
#pragma unroll
  for (int i = 0; i < 2; ++i) {
    const int l = t + 512 * i;
    const float4* xr = (const float4*)(x + ((size_t)b * NS + 1024 + l) * 8);
    pf[i][0] = xr[0];
    pf[i][1] = xr[1];
  }

  // ---- loop-invariant score B-fragments: Q[n][d]*QS (g==0 lanes only) ----
  h4 Bq0 = {(f16)0.f, (f16)0.f, (f16)0.f, (f16)0.f};
  h4 Bq1 = Bq0;
  if (g == 0) {
    const float4* xq = (const float4*)(
        x + ((size_t)b * NS + blockIdx.x * 128 + w * 16 + n) * 8);
    float4 lo = xq[0], hi = xq[1];
    Bq0[0] = (f16)(__cosf(lo.x + th[0]) * QS);
    Bq0[1] = (f16)(__cosf(lo.y + th[1]) * QS);
    Bq0[2] = (f16)(__cosf(lo.z + th[2]) * QS);
    Bq0[3] = (f16)(__cosf(lo.w + th[3]) * QS);
    Bq1[0] = (f16)(__cosf(hi.x + th[4]) * QS);
    Bq1[1] = (f16)(__cosf(hi.y + th[5]) * QS);
    Bq1[2] = (f16)(__cosf(hi.z + th[6]) * QS);
    Bq1[3] = (f16)(__cosf(hi.w + th[7]) * QS);
  }

  // score A-frag source: g==0 lanes read k-row (r0+n) (both heads in one
  // b128), advancing 16 rows (=128 halves)/block; g>0 read the zeros row.
  const int sini = (g == 0) ? n * 8 : ZIDX;
  const int sadv = (g == 0) ? 128 : 0;

  // PV A-frag source rows in the transposed copy, per head:
  //   m<4 -> dim (head*4+m); m==4 -> ones; m>4 -> zeros
  const int d0 = (n < 4) ? n : ((n == 4) ? 8 : 9);
  const int d1 = (n < 4) ? (n + 4) : d0;
  const int t0ini = TR_BASE + d0 * TR_STRIDE + 4 * g;
  const int t1ini = TR_BASE + d1 * TR_STRIDE + 4 * g;

  const f32x4 Z = {0.f, 0.f, 0.f, 0.f};
  f32x4 C0 = Z;  // head0: rows 0-3 = dims, row 4 = den (col = q)
  f32x4 C1 = Z;  // head1

  __syncthreads();  // (1) chunk 0 staged

  for (int chunk = 0; chunk < 2; ++chunk) {
    if (chunk == 1) {
      __syncthreads();  // (2) chunk 0 fully consumed
#pragma unroll
      for (int i = 0; i < 2; ++i) {
        const int l = t + 512 * i;
        float4 lo = pf[i][0], hi = pf[i][1];
        h8 hv;
        hv[0] = (f16)__cosf(lo.x + th[0]);
        hv[1] = (f16)__cosf(lo.y + th[1]);
        hv[2] = (f16)__cosf(lo.z + th[2]);
        hv[3] = (f16)__cosf(lo.w + th[3]);
        hv[4] = (f16)__cosf(hi.x + th[4]);
        hv[5] = (f16)__cosf(hi.y + th[5]);
        hv[6] = (f16)__cosf(hi.z + th[6]);
        hv[7] = (f16)__cosf(hi.w + th[7]);
        ((h8*)lds)[l] = hv;
#pragma unroll
        for (int e = 0; e < 8; ++e) lds[TR_BASE + e * TR_STRIDE + l] = hv[e];
      }
      __syncthreads();  // (3) chunk 1 staged
    }

    int sa = sini;
    int ta0 = t0ini;
    int ta1 = t1ini;
#pragma unroll 4
    for (int kk = 0; kk < 64; ++kk) {
      // one b128: head0 dims in halves 0-3, head1 in 4-7 (zeros for g>0)
      h8 kr = *(const h8*)(lds + sa);
      h4 a0 = __builtin_shufflevector(kr, kr, 0, 1, 2, 3);
      h4 a1 = __builtin_shufflevector(kr, kr, 4, 5, 6, 7);
      // PV A-frags: h^T (+ones/zeros) at cols r0+4g..+3, one b64 per head
      h4 v0 = *(const h4*)(lds + ta0);
      h4 v1 = *(const h4*)(lds + ta1);

      // scores: D row = k-offset 4g+reg, col = q
      f32x4 S0 = mfma16(a0, Bq0, Z);
      f32x4 S1 = mfma16(a1, Bq1, Z);

      // exp (trans pipe) + pack: h4 IS the PV B-fragment
      h4 p0, p1;
      h2 u;
      u = cvt_pk_f16(__builtin_amdgcn_exp2f(S0[0]),
                     __builtin_amdgcn_exp2f(S0[1]));
      p0[0] = u[0];
      p0[1] = u[1];
      u = cvt_pk_f16(__builtin_amdgcn_exp2f(S0[2]),
                     __builtin_amdgcn_exp2f(S0[3]));
      p0[2] = u[0];
      p0[3] = u[1];
      u = cvt_pk_f16(__builtin_amdgcn_exp2f(S1[0]),
                     __builtin_amdgcn_exp2f(S1[1]));
      p1[0] = u[0];
      p1[1] = u[1];
      u = cvt_pk_f16(__builtin_amdgcn_exp2f(S1[2]),
                     __builtin_amdgcn_exp2f(S1[3]));
      p1[2] = u[0];
      p1[3] = u[1];

      // PV (+denominator via ones-row) on the MFMA pipe
      C0 = mfma16(v0, p0, C0);
      C1 = mfma16(v1, p1, C1);

      sa += sadv;
      ta0 += 16;
      ta1 += 16;
    }
  }

  // ---- per-wave epilogue: C cols = q (lane&15), rows = 4*(lane>>4)+reg ----
  const float den0 = __shfl(C0[0], 16 + n, 64);  // row 4 = ones-row sum
  const float den1 = __shfl(C1[0], 16 + n, 64);
  if (lane < 16) {  // group 0 holds rows 0-3 = numerator dims
    const float i0 = 1.0f / den0, i1 = 1.0f / den1;
    float m8[8] = {C0[0] * i0, C0[1] * i0, C0[2] * i0, C0[3] * i0,
                   C1[0] * i1, C1[1] * i1, C1[2] * i1, C1[3] * i1};
    float o[8];
#pragma unroll
    for (int e = 0; e < 8; ++e) {
      float s = 0.f;
#pragma unroll
      for (int f = 0; f < 8; ++f) s += m8[f] * Wout[e * 8 + f];
      o[e] = s;
    }
    const int q = blockIdx.x * 128 + w * 16 + n;
    float4* op = (float4*)(outp + ((size_t)b * NS + q) * 8);
    op[0] = make_float4(o[0], o[1], o[2], o[3]);
    op[1] = make_float4(o[4], o[5], o[6], o[7]);
  }
}

extern "C" void kernel_launch(void* const* d_in, const int* in_sizes, int n_in,
                              void* d_out, int out_size, void* d_ws,
                              size_t ws_size, hipStream_t stream) {
  const float* x = (const float*)d_in[0];      // [32, 2048, 8]
  const float* theta = (const float*)d_in[1];  // [8]
  const float* W = (const float*)d_in[2];      // [8, 8]
  float* out = (float*)d_out;                  // [32, 2048, 8]
  (void)d_ws;
  (void)ws_size;

  // 512 blocks (16 q-supertiles x 32 batches) of 8 waves; 37.4 KB LDS each
  // -> 2 blocks/CU, 16 waves/CU = 4 waves/SIMD (VGPR cap 128: no spills).
  attn_fused_kernel<<<dim3(NS / 128, NB), 512, 0, stream>>>(x, theta, W, out);
}